// Round 9
// baseline (3783.043 us; speedup 1.0000x reference)
//
#include <hip/hip_runtime.h>

#define N_NODES 100000
#define N_EDGES 1600000
#define IN_CH   128
#define HID     64
#define NG      256
#define NFILL   4    // dst-range passes for L2-resident scatter
#define CAP     64   // padded CSR slots per node (max deg ~42 for Poisson(16))

// ---- round-to-nearest-even f32 -> bf16 bits ----
__device__ __forceinline__ unsigned short f2bf(float f) {
    union { float f; unsigned u; } v; v.f = f;
    unsigned r = v.u + 0x7FFF + ((v.u >> 16) & 1);
    return (unsigned short)(r >> 16);
}
__device__ __forceinline__ unsigned int f2bf2(float lo, float hi) {
    return (unsigned int)f2bf(lo) | ((unsigned int)f2bf(hi) << 16);
}
__device__ __forceinline__ float bf_lo(unsigned int p) { return __uint_as_float(p << 16); }
__device__ __forceinline__ float bf_hi(unsigned int p) { return __uint_as_float(p & 0xFFFF0000u); }

// ---- padded CSR fill (range pass): count + place in one atomic ----
__global__ void k_fill(const int* __restrict__ src, const int* __restrict__ dst,
                       int* __restrict__ fillpos, int* __restrict__ col,
                       int lo, int hi) {
    int e = blockIdx.x * blockDim.x + threadIdx.x;
    if (e >= N_EDGES) return;
    int d = dst[e];
    if (d < lo || d >= hi) return;
    int p = atomicAdd(&fillpos[d], 1);
    if (p < CAP) col[(long)d * CAP + p] = src[e];
}

// ---- dinv[i] = rsqrt(deg[i] + 1); deg == fillpos after fills ----
__global__ void k_dinv(const int* __restrict__ deg, float* __restrict__ dinv) {
    int i = blockIdx.x * blockDim.x + threadIdx.x;
    if (i < N_NODES) dinv[i] = rsqrtf((float)deg[i] + 1.0f);
}

// ---- linear v4: register-blocked GEMM. 1 wave/block = 64-node x 64-ch tile.
// Lane (ir,jr) owns 8x8 sub-tile. x staged TRANSPOSED in LDS (xs[k][node]) so
// A-frags are per-lane-distinct ds_read_b128 (no broadcast waste); W from
// global (L1-hot). hs[i][j] = bf16( dinv[i] * sum_k x[i][k]*W[k][j] )
template <int K>
__global__ void __launch_bounds__(64) k_linear(const float* __restrict__ x,
                                               const float* __restrict__ W,
                                               const float* __restrict__ dinv,
                                               unsigned short* __restrict__ hs) {
    __shared__ float xs[2][32][68];   // [buf][k][node(+pad)] 17.4KB
    const int lane = threadIdx.x;
    const int ir = lane >> 3;         // node-group 0..7
    const int jr = lane & 7;          // channel-group 0..7
    const int n0 = blockIdx.x * 64;

    // staging: 8 iters, each covers 8 rows x 32 k, coalesced 128B/row reads
    auto stage = [&](int buf, int k0) {
        const int rsub = lane >> 3;       // 0..7
        const int kq = (lane & 7) * 4;    // 0,4,..28
#pragma unroll
        for (int it = 0; it < 8; ++it) {
            int r = it * 8 + rsub;
            int rr = n0 + r;
            rr = rr < N_NODES ? rr : N_NODES - 1;
            float4 v = *reinterpret_cast<const float4*>(&x[(long)rr * K + k0 + kq]);
            xs[buf][kq + 0][r] = v.x;
            xs[buf][kq + 1][r] = v.y;
            xs[buf][kq + 2][r] = v.z;
            xs[buf][kq + 3][r] = v.w;
        }
    };

    float acc[8][8];
#pragma unroll
    for (int r = 0; r < 8; ++r)
#pragma unroll
        for (int c = 0; c < 8; ++c) acc[r][c] = 0.f;

    const int NC = K / 32;
    stage(0, 0);
    __syncthreads();
#pragma unroll
    for (int ch = 0; ch < NC; ++ch) {
        if (ch + 1 < NC) stage((ch + 1) & 1, (ch + 1) * 32);
        const int buf = ch & 1;
        const int k0 = ch * 32;
#pragma unroll
        for (int k = 0; k < 32; ++k) {
            float4 a0 = *reinterpret_cast<const float4*>(&xs[buf][k][ir * 8]);
            float4 a1 = *reinterpret_cast<const float4*>(&xs[buf][k][ir * 8 + 4]);
            const float4* Wk = reinterpret_cast<const float4*>(&W[(long)(k0 + k) * 64 + jr * 8]);
            float4 b0 = Wk[0];
            float4 b1 = Wk[1];
            float ar[8] = {a0.x, a0.y, a0.z, a0.w, a1.x, a1.y, a1.z, a1.w};
            float bc[8] = {b0.x, b0.y, b0.z, b0.w, b1.x, b1.y, b1.z, b1.w};
#pragma unroll
            for (int r = 0; r < 8; ++r)
#pragma unroll
                for (int c = 0; c < 8; ++c)
                    acc[r][c] = fmaf(ar[r], bc[c], acc[r][c]);
        }
        __syncthreads();
    }

    // epilogue: scale by dinv, pack bf16x8 per row, one 16B store per row
#pragma unroll
    for (int r = 0; r < 8; ++r) {
        int n = n0 + ir * 8 + r;
        if (n >= N_NODES) break;
        float d = dinv[n];
        uint4 p;
        p.x = f2bf2(acc[r][0] * d, acc[r][1] * d);
        p.y = f2bf2(acc[r][2] * d, acc[r][3] * d);
        p.z = f2bf2(acc[r][4] * d, acc[r][5] * d);
        p.w = f2bf2(acc[r][6] * d, acc[r][7] * d);
        *reinterpret_cast<uint4*>(&hs[(long)n * 64 + jr * 8]) = p;
    }
}

// ---- fused gather + self-loop + bias + relu; 2 nodes per wave, bf16x2/lane ----
// out[i][j] = relu( dinv[i] * ( sum_e hs[col[e]][j] + hs[i][j] ) + b[j] )
__global__ void k_gather(const int* __restrict__ deg, const int* __restrict__ col,
                         const unsigned int* __restrict__ hs2,   // packed bf16x2, 32/row
                         const float* __restrict__ dinv, const float* __restrict__ bias,
                         float* __restrict__ out) {
    int t = blockIdx.x * blockDim.x + threadIdx.x;
    int lane = t & 63;
    int half = lane >> 5;           // which node of the wave's pair
    int c2 = lane & 31;             // channel-pair index (channels 2c2, 2c2+1)
    int i = ((t >> 6) << 1) + half; // node
    if (i >= N_NODES) return;
    const int* crow = col + (long)i * CAP;
    int n = deg[i];
    n = n < CAP ? n : CAP;
    unsigned int self = hs2[(long)i * 32 + c2];
    float aL = bf_lo(self), aH = bf_hi(self);
    int e = 0;
    for (; e + 4 <= n; e += 4) {
        int s0 = crow[e + 0], s1 = crow[e + 1];
        int s2 = crow[e + 2], s3 = crow[e + 3];
        unsigned int v0 = hs2[(long)s0 * 32 + c2];
        unsigned int v1 = hs2[(long)s1 * 32 + c2];
        unsigned int v2 = hs2[(long)s2 * 32 + c2];
        unsigned int v3 = hs2[(long)s3 * 32 + c2];
        aL += bf_lo(v0); aH += bf_hi(v0);
        aL += bf_lo(v1); aH += bf_hi(v1);
        aL += bf_lo(v2); aH += bf_hi(v2);
        aL += bf_lo(v3); aH += bf_hi(v3);
    }
    for (; e < n; ++e) {
        unsigned int v = hs2[(long)crow[e] * 32 + c2];
        aL += bf_lo(v); aH += bf_hi(v);
    }
    float di = dinv[i];
    float vL = fmaf(di, aL, bias[2 * c2]);
    float vH = fmaf(di, aH, bias[2 * c2 + 1]);
    float2 o;
    o.x = vL > 0.f ? vL : 0.f;
    o.y = vH > 0.f ? vH : 0.f;
    *reinterpret_cast<float2*>(&out[(long)i * 64 + 2 * c2]) = o;
}

// ---- graph boundaries from sorted batch ----
__global__ void k_bounds(const int* __restrict__ batch, int* __restrict__ start) {
    int i = blockIdx.x * blockDim.x + threadIdx.x;
    if (i >= N_NODES) return;
    int b = batch[i];
    int prev = (i == 0) ? -1 : batch[i - 1];
    for (int g = prev + 1; g <= b; ++g) start[g] = i;
    if (i == N_NODES - 1)
        for (int g = b + 1; g <= NG; ++g) start[g] = N_NODES;
}

// ---- fused mean-pool + head MLP: one 256-thread block per graph ----
__global__ void k_poolhead(const float* __restrict__ a, const int* __restrict__ start,
                           const float* __restrict__ Wc1, const float* __restrict__ bc1,
                           const float* __restrict__ Wc2, const float* __restrict__ bc2,
                           float* __restrict__ out) {
    __shared__ float partial[4][64];
    __shared__ float gvec[64];
    __shared__ float tvec[32];
    int g = blockIdx.x;
    int w = threadIdx.x >> 6;
    int j = threadIdx.x & 63;
    int s0 = start[g], s1 = start[g + 1];
    float acc = 0.f;
    for (int i = s0 + w; i < s1; i += 4)
        acc += a[(long)i * 64 + j];
    partial[w][j] = acc;
    __syncthreads();
    if (w == 0) {
        float c = (float)(s1 - s0);
        c = c > 1.f ? c : 1.f;
        gvec[j] = (partial[0][j] + partial[1][j] + partial[2][j] + partial[3][j]) / c;
    }
    __syncthreads();
    if (threadIdx.x < 32) {
        int jj = threadIdx.x;
        float acc2 = bc1[jj];
#pragma unroll 8
        for (int k = 0; k < 64; ++k) acc2 = fmaf(gvec[k], Wc1[k * 32 + jj], acc2);
        tvec[jj] = acc2 > 0.f ? acc2 : 0.f;
    }
    __syncthreads();
    if (threadIdx.x < 2) {
        int jj = threadIdx.x;
        float acc2 = bc2[jj];
#pragma unroll
        for (int k = 0; k < 32; ++k) acc2 = fmaf(tvec[k], Wc2[k * 2 + jj], acc2);
        out[g * 2 + jj] = acc2;
    }
}

extern "C" void kernel_launch(void* const* d_in, const int* in_sizes, int n_in,
                              void* d_out, int out_size, void* d_ws, size_t ws_size,
                              hipStream_t stream) {
    const float* x    = (const float*)d_in[0];
    const int*   ei   = (const int*)d_in[1];
    const int*   batch= (const int*)d_in[2];
    const float* W1   = (const float*)d_in[3];
    const float* b1   = (const float*)d_in[4];
    const float* W2   = (const float*)d_in[5];
    const float* b2   = (const float*)d_in[6];
    const float* Wc1  = (const float*)d_in[7];
    const float* bc1  = (const float*)d_in[8];
    const float* Wc2  = (const float*)d_in[9];
    const float* bc2  = (const float*)d_in[10];
    float* out = (float*)d_out;

    const int* src = ei;            // edge_index[0]
    const int* dst = ei + N_EDGES;  // edge_index[1]

    char* ws = (char*)d_ws;
    size_t off = 0;
    auto alloc = [&](size_t bytes) {
        void* p = ws + off;
        off += (bytes + 255) & ~(size_t)255;
        return p;
    };
    unsigned short* hs = (unsigned short*)alloc((size_t)N_NODES * HID * 2);   // 12.8MB bf16
    float* agg     = (float*)alloc((size_t)N_NODES * HID * sizeof(float));    // 25.6MB
    int*   col     = (int*)  alloc((size_t)N_NODES * CAP * sizeof(int));      // 25.6MB padded CSR
    float* dinv    = (float*)alloc(N_NODES * sizeof(float));
    int*   fillpos = (int*)  alloc(N_NODES * sizeof(int));   // becomes deg
    int*   start   = (int*)  alloc((NG + 1) * sizeof(int));

    const int TB = 256;

    // padded CSR build: fill counts + places in one pass-family
    hipMemsetAsync(fillpos, 0, N_NODES * sizeof(int), stream);
    {
        const int step = (N_NODES + NFILL - 1) / NFILL;
        for (int p = 0; p < NFILL; ++p) {
            int lo = p * step;
            int hi = lo + step < N_NODES ? lo + step : N_NODES;
            k_fill<<<(N_EDGES + TB - 1) / TB, TB, 0, stream>>>(src, dst, fillpos, col, lo, hi);
        }
    }
    k_dinv<<<(N_NODES + TB - 1) / TB, TB, 0, stream>>>(fillpos, dinv);

    // graph boundaries
    k_bounds<<<(N_NODES + TB - 1) / TB, TB, 0, stream>>>(batch, start);

    const int gatherBlocks = ((N_NODES + 1) / 2 * 64 + TB - 1) / TB;
    const int linBlocks = (N_NODES + 63) / 64;

    // layer 1
    k_linear<IN_CH><<<linBlocks, 64, 0, stream>>>(x, W1, dinv, hs);
    k_gather<<<gatherBlocks, TB, 0, stream>>>(fillpos, col, (const unsigned int*)hs, dinv, b1, agg);

    // layer 2
    k_linear<HID><<<linBlocks, 64, 0, stream>>>(agg, W2, dinv, hs);
    k_gather<<<gatherBlocks, TB, 0, stream>>>(fillpos, col, (const unsigned int*)hs, dinv, b2, agg);

    // fused mean-pool + head
    k_poolhead<<<NG, 256, 0, stream>>>(agg, start, Wc1, bc1, Wc2, bc2, out);
}

// Round 10
// 294.622 us; speedup vs baseline: 12.8403x; 12.8403x over previous
//
#include <hip/hip_runtime.h>

#define N_NODES 100000
#define N_EDGES 1600000
#define IN_CH   128
#define HID     64
#define NG      256
#define NFILL   4    // dst-range passes for L2-resident scatter
#define CAP     64   // padded CSR slots per node (max deg ~42 for Poisson(16))

// ---- round-to-nearest-even f32 -> bf16 bits ----
__device__ __forceinline__ unsigned short f2bf(float f) {
    union { float f; unsigned u; } v; v.f = f;
    unsigned r = v.u + 0x7FFF + ((v.u >> 16) & 1);
    return (unsigned short)(r >> 16);
}
__device__ __forceinline__ unsigned int f2bf2(float lo, float hi) {
    return (unsigned int)f2bf(lo) | ((unsigned int)f2bf(hi) << 16);
}
__device__ __forceinline__ float bf_lo(unsigned int p) { return __uint_as_float(p << 16); }
__device__ __forceinline__ float bf_hi(unsigned int p) { return __uint_as_float(p & 0xFFFF0000u); }

// ---- padded CSR fill (range pass): count + place in one atomic ----
__global__ void k_fill(const int* __restrict__ src, const int* __restrict__ dst,
                       int* __restrict__ fillpos, int* __restrict__ col,
                       int lo, int hi) {
    int e = blockIdx.x * blockDim.x + threadIdx.x;
    if (e >= N_EDGES) return;
    int d = dst[e];
    if (d < lo || d >= hi) return;
    int p = atomicAdd(&fillpos[d], 1);
    if (p < CAP) col[(long)d * CAP + p] = src[e];
}

// ---- dinv[i] = rsqrt(deg[i] + 1); deg == fillpos after fills ----
__global__ void k_dinv(const int* __restrict__ deg, float* __restrict__ dinv) {
    int i = blockIdx.x * blockDim.x + threadIdx.x;
    if (i < N_NODES) dinv[i] = rsqrtf((float)deg[i] + 1.0f);
}

// ---- linear v5: register-blocked GEMM, SINGLE-buffered (spill-safe).
// 1 wave/block = 64-node x 64-ch tile; lane (ir,jr) owns 8x8 sub-tile.
// x staged transposed (xs[k][node]) -> per-lane-distinct ds_read_b128;
// W from global (L1-hot). hs[i][j] = bf16( dinv[i]*sum_k x[i][k]*W[k][j] )
template <int K>
__global__ void __launch_bounds__(64) k_linear(const float* __restrict__ x,
                                               const float* __restrict__ W,
                                               const float* __restrict__ dinv,
                                               unsigned short* __restrict__ hs) {
    __shared__ float xs[32][68];      // [k][node(+pad)] 8.7KB
    const int lane = threadIdx.x;
    const int ir = lane >> 3;         // node-group 0..7
    const int jr = lane & 7;          // channel-group 0..7
    const int n0 = blockIdx.x * 64;

    float acc[8][8];
#pragma unroll
    for (int r = 0; r < 8; ++r)
#pragma unroll
        for (int c = 0; c < 8; ++c) acc[r][c] = 0.f;

    const int NC = K / 32;
    for (int ch = 0; ch < NC; ++ch) {
        const int k0 = ch * 32;
        // stage chunk: 8 iters, 8 rows x 32 k each, coalesced 128B/row
        {
            const int rsub = lane >> 3;       // 0..7
            const int kq = (lane & 7) * 4;    // 0,4,..28
#pragma unroll
            for (int it = 0; it < 8; ++it) {
                int r = it * 8 + rsub;
                int rr = n0 + r;
                rr = rr < N_NODES ? rr : N_NODES - 1;
                float4 v = *reinterpret_cast<const float4*>(&x[(long)rr * K + k0 + kq]);
                xs[kq + 0][r] = v.x;
                xs[kq + 1][r] = v.y;
                xs[kq + 2][r] = v.z;
                xs[kq + 3][r] = v.w;
            }
        }
        __syncthreads();
#pragma unroll
        for (int k = 0; k < 32; ++k) {
            float4 a0 = *reinterpret_cast<const float4*>(&xs[k][ir * 8]);
            float4 a1 = *reinterpret_cast<const float4*>(&xs[k][ir * 8 + 4]);
            const float4* Wk = reinterpret_cast<const float4*>(&W[(long)(k0 + k) * 64 + jr * 8]);
            float4 b0 = Wk[0];
            float4 b1 = Wk[1];
            float bv0 = b0.x, bv1 = b0.y, bv2 = b0.z, bv3 = b0.w;
            float bv4 = b1.x, bv5 = b1.y, bv6 = b1.z, bv7 = b1.w;
#define GCN_ROW(r, av)                                             \
            acc[r][0] = fmaf(av, bv0, acc[r][0]);                  \
            acc[r][1] = fmaf(av, bv1, acc[r][1]);                  \
            acc[r][2] = fmaf(av, bv2, acc[r][2]);                  \
            acc[r][3] = fmaf(av, bv3, acc[r][3]);                  \
            acc[r][4] = fmaf(av, bv4, acc[r][4]);                  \
            acc[r][5] = fmaf(av, bv5, acc[r][5]);                  \
            acc[r][6] = fmaf(av, bv6, acc[r][6]);                  \
            acc[r][7] = fmaf(av, bv7, acc[r][7]);
            GCN_ROW(0, a0.x) GCN_ROW(1, a0.y) GCN_ROW(2, a0.z) GCN_ROW(3, a0.w)
            GCN_ROW(4, a1.x) GCN_ROW(5, a1.y) GCN_ROW(6, a1.z) GCN_ROW(7, a1.w)
#undef GCN_ROW
        }
        __syncthreads();
    }

    // epilogue: scale by dinv, pack bf16x8 per row, one 16B store per row
#pragma unroll
    for (int r = 0; r < 8; ++r) {
        int n = n0 + ir * 8 + r;
        if (n < N_NODES) {
            float d = dinv[n];
            uint4 p;
            p.x = f2bf2(acc[r][0] * d, acc[r][1] * d);
            p.y = f2bf2(acc[r][2] * d, acc[r][3] * d);
            p.z = f2bf2(acc[r][4] * d, acc[r][5] * d);
            p.w = f2bf2(acc[r][6] * d, acc[r][7] * d);
            *reinterpret_cast<uint4*>(&hs[(long)n * 64 + jr * 8]) = p;
        }
    }
}

// ---- fused gather + self-loop + bias + relu; 2 nodes per wave, bf16x2/lane ----
// out[i][j] = relu( dinv[i] * ( sum_e hs[col[e]][j] + hs[i][j] ) + b[j] )
__global__ void k_gather(const int* __restrict__ deg, const int* __restrict__ col,
                         const unsigned int* __restrict__ hs2,   // packed bf16x2, 32/row
                         const float* __restrict__ dinv, const float* __restrict__ bias,
                         float* __restrict__ out) {
    int t = blockIdx.x * blockDim.x + threadIdx.x;
    int lane = t & 63;
    int half = lane >> 5;           // which node of the wave's pair
    int c2 = lane & 31;             // channel-pair index (channels 2c2, 2c2+1)
    int i = ((t >> 6) << 1) + half; // node
    if (i >= N_NODES) return;
    const int* crow = col + (long)i * CAP;
    int n = deg[i];
    n = n < CAP ? n : CAP;
    unsigned int self = hs2[(long)i * 32 + c2];
    float aL = bf_lo(self), aH = bf_hi(self);
    int e = 0;
    for (; e + 4 <= n; e += 4) {
        int s0 = crow[e + 0], s1 = crow[e + 1];
        int s2 = crow[e + 2], s3 = crow[e + 3];
        unsigned int v0 = hs2[(long)s0 * 32 + c2];
        unsigned int v1 = hs2[(long)s1 * 32 + c2];
        unsigned int v2 = hs2[(long)s2 * 32 + c2];
        unsigned int v3 = hs2[(long)s3 * 32 + c2];
        aL += bf_lo(v0); aH += bf_hi(v0);
        aL += bf_lo(v1); aH += bf_hi(v1);
        aL += bf_lo(v2); aH += bf_hi(v2);
        aL += bf_lo(v3); aH += bf_hi(v3);
    }
    for (; e < n; ++e) {
        unsigned int v = hs2[(long)crow[e] * 32 + c2];
        aL += bf_lo(v); aH += bf_hi(v);
    }
    float di = dinv[i];
    float vL = fmaf(di, aL, bias[2 * c2]);
    float vH = fmaf(di, aH, bias[2 * c2 + 1]);
    float2 o;
    o.x = vL > 0.f ? vL : 0.f;
    o.y = vH > 0.f ? vH : 0.f;
    *reinterpret_cast<float2*>(&out[(long)i * 64 + 2 * c2]) = o;
}

// ---- graph boundaries from sorted batch ----
__global__ void k_bounds(const int* __restrict__ batch, int* __restrict__ start) {
    int i = blockIdx.x * blockDim.x + threadIdx.x;
    if (i >= N_NODES) return;
    int b = batch[i];
    int prev = (i == 0) ? -1 : batch[i - 1];
    for (int g = prev + 1; g <= b; ++g) start[g] = i;
    if (i == N_NODES - 1)
        for (int g = b + 1; g <= NG; ++g) start[g] = N_NODES;
}

// ---- fused mean-pool + head MLP: one 256-thread block per graph ----
__global__ void k_poolhead(const float* __restrict__ a, const int* __restrict__ start,
                           const float* __restrict__ Wc1, const float* __restrict__ bc1,
                           const float* __restrict__ Wc2, const float* __restrict__ bc2,
                           float* __restrict__ out) {
    __shared__ float partial[4][64];
    __shared__ float gvec[64];
    __shared__ float tvec[32];
    int g = blockIdx.x;
    int w = threadIdx.x >> 6;
    int j = threadIdx.x & 63;
    int s0 = start[g], s1 = start[g + 1];
    float acc = 0.f;
    for (int i = s0 + w; i < s1; i += 4)
        acc += a[(long)i * 64 + j];
    partial[w][j] = acc;
    __syncthreads();
    if (w == 0) {
        float c = (float)(s1 - s0);
        c = c > 1.f ? c : 1.f;
        gvec[j] = (partial[0][j] + partial[1][j] + partial[2][j] + partial[3][j]) / c;
    }
    __syncthreads();
    if (threadIdx.x < 32) {
        int jj = threadIdx.x;
        float acc2 = bc1[jj];
#pragma unroll 8
        for (int k = 0; k < 64; ++k) acc2 = fmaf(gvec[k], Wc1[k * 32 + jj], acc2);
        tvec[jj] = acc2 > 0.f ? acc2 : 0.f;
    }
    __syncthreads();
    if (threadIdx.x < 2) {
        int jj = threadIdx.x;
        float acc2 = bc2[jj];
#pragma unroll
        for (int k = 0; k < 32; ++k) acc2 = fmaf(tvec[k], Wc2[k * 2 + jj], acc2);
        out[g * 2 + jj] = acc2;
    }
}

extern "C" void kernel_launch(void* const* d_in, const int* in_sizes, int n_in,
                              void* d_out, int out_size, void* d_ws, size_t ws_size,
                              hipStream_t stream) {
    const float* x    = (const float*)d_in[0];
    const int*   ei   = (const int*)d_in[1];
    const int*   batch= (const int*)d_in[2];
    const float* W1   = (const float*)d_in[3];
    const float* b1   = (const float*)d_in[4];
    const float* W2   = (const float*)d_in[5];
    const float* b2   = (const float*)d_in[6];
    const float* Wc1  = (const float*)d_in[7];
    const float* bc1  = (const float*)d_in[8];
    const float* Wc2  = (const float*)d_in[9];
    const float* bc2  = (const float*)d_in[10];
    float* out = (float*)d_out;

    const int* src = ei;            // edge_index[0]
    const int* dst = ei + N_EDGES;  // edge_index[1]

    char* ws = (char*)d_ws;
    size_t off = 0;
    auto alloc = [&](size_t bytes) {
        void* p = ws + off;
        off += (bytes + 255) & ~(size_t)255;
        return p;
    };
    unsigned short* hs = (unsigned short*)alloc((size_t)N_NODES * HID * 2);   // 12.8MB bf16
    float* agg     = (float*)alloc((size_t)N_NODES * HID * sizeof(float));    // 25.6MB
    int*   col     = (int*)  alloc((size_t)N_NODES * CAP * sizeof(int));      // 25.6MB padded CSR
    float* dinv    = (float*)alloc(N_NODES * sizeof(float));
    int*   fillpos = (int*)  alloc(N_NODES * sizeof(int));   // becomes deg
    int*   start   = (int*)  alloc((NG + 1) * sizeof(int));

    const int TB = 256;

    // padded CSR build: fill counts + places in one pass-family
    hipMemsetAsync(fillpos, 0, N_NODES * sizeof(int), stream);
    {
        const int step = (N_NODES + NFILL - 1) / NFILL;
        for (int p = 0; p < NFILL; ++p) {
            int lo = p * step;
            int hi = lo + step < N_NODES ? lo + step : N_NODES;
            k_fill<<<(N_EDGES + TB - 1) / TB, TB, 0, stream>>>(src, dst, fillpos, col, lo, hi);
        }
    }
    k_dinv<<<(N_NODES + TB - 1) / TB, TB, 0, stream>>>(fillpos, dinv);

    // graph boundaries
    k_bounds<<<(N_NODES + TB - 1) / TB, TB, 0, stream>>>(batch, start);

    const int gatherBlocks = ((N_NODES + 1) / 2 * 64 + TB - 1) / TB;
    const int linBlocks = (N_NODES + 63) / 64;

    // layer 1
    k_linear<IN_CH><<<linBlocks, 64, 0, stream>>>(x, W1, dinv, hs);
    k_gather<<<gatherBlocks, TB, 0, stream>>>(fillpos, col, (const unsigned int*)hs, dinv, b1, agg);

    // layer 2
    k_linear<HID><<<linBlocks, 64, 0, stream>>>(agg, W2, dinv, hs);
    k_gather<<<gatherBlocks, TB, 0, stream>>>(fillpos, col, (const unsigned int*)hs, dinv, b2, agg);

    // fused mean-pool + head
    k_poolhead<<<NG, 256, 0, stream>>>(agg, start, Wc1, bc1, Wc2, bc2, out);
}